// Round 3
// baseline (739.240 us; speedup 1.0000x reference)
//
#include <hip/hip_runtime.h>

#define B_  4
#define C_  256     // C_IN == LATENT == 256
#define N_  4096    // H*W
#define SCALE 0.0625f   // 1/sqrt(256)

typedef short s8v __attribute__((ext_vector_type(8)));
typedef float f4v __attribute__((ext_vector_type(4)));

// round-to-nearest-even fp32 -> bf16 (values are finite; no NaN handling needed)
static __device__ __forceinline__ ushort f2bf(float f) {
  union { float f; uint u; } v; v.f = f;
  return (ushort)((v.u + 0x7FFFu + ((v.u >> 16) & 1u)) >> 16);
}

// ---------------------------------------------------------------------------
// QKV projection, fp32 compute, bf16 outputs (unchanged from R1/R2 — correct).
//   q,k written TRANSPOSED as [b][n][latent]; v natural [b][latent][n].
// grid (4, 32, 12), block 256.
// ---------------------------------------------------------------------------
__global__ __launch_bounds__(256) void qkv_proj(
    const float* __restrict__ x,
    const float* __restrict__ Wq, const float* __restrict__ bq,
    const float* __restrict__ Wk, const float* __restrict__ bk,
    const float* __restrict__ Wv, const float* __restrict__ bv,
    ushort* __restrict__ q_t, ushort* __restrict__ k_t, ushort* __restrict__ v_bf)
{
  const int p = blockIdx.z >> 2;
  const int b = blockIdx.z & 3;
  const float* W  = (p == 0) ? Wq : (p == 1) ? Wk : Wv;
  const float* bi = (p == 0) ? bq : (p == 1) ? bk : bv;
  const int l0 = blockIdx.y * 8;
  const int n  = blockIdx.x * 1024 + threadIdx.x * 4;

  __shared__ float w_lds[8 * 256];
  for (int i = threadIdx.x; i < 2048; i += 256) w_lds[i] = W[l0 * 256 + i];
  __syncthreads();

  float acc[8][4];
  #pragma unroll
  for (int r = 0; r < 8; ++r) { acc[r][0]=0.f; acc[r][1]=0.f; acc[r][2]=0.f; acc[r][3]=0.f; }

  const float* xp = x + (size_t)b * ((size_t)C_ * N_) + n;
  for (int c4 = 0; c4 < 256; c4 += 4) {
    float4 x0 = *(const float4*)(xp + (size_t)(c4 + 0) * N_);
    float4 x1 = *(const float4*)(xp + (size_t)(c4 + 1) * N_);
    float4 x2 = *(const float4*)(xp + (size_t)(c4 + 2) * N_);
    float4 x3 = *(const float4*)(xp + (size_t)(c4 + 3) * N_);
    #pragma unroll
    for (int r = 0; r < 8; ++r) {
      float4 w = *(const float4*)&w_lds[r * 256 + c4];
      acc[r][0] += w.x * x0.x + w.y * x1.x + w.z * x2.x + w.w * x3.x;
      acc[r][1] += w.x * x0.y + w.y * x1.y + w.z * x2.y + w.w * x3.y;
      acc[r][2] += w.x * x0.z + w.y * x1.z + w.z * x2.z + w.w * x3.z;
      acc[r][3] += w.x * x0.w + w.y * x1.w + w.z * x2.w + w.w * x3.w;
    }
  }

  if (p < 2) {
    ushort* outp = (p == 0) ? q_t : k_t;
    #pragma unroll
    for (int j = 0; j < 4; ++j) {
      uint u0 = (uint)f2bf(acc[0][j] + bi[l0+0]) | ((uint)f2bf(acc[1][j] + bi[l0+1]) << 16);
      uint u1 = (uint)f2bf(acc[2][j] + bi[l0+2]) | ((uint)f2bf(acc[3][j] + bi[l0+3]) << 16);
      uint u2 = (uint)f2bf(acc[4][j] + bi[l0+4]) | ((uint)f2bf(acc[5][j] + bi[l0+5]) << 16);
      uint u3 = (uint)f2bf(acc[6][j] + bi[l0+6]) | ((uint)f2bf(acc[7][j] + bi[l0+7]) << 16);
      *(uint4*)(outp + (size_t)(b * N_ + n + j) * C_ + l0) = make_uint4(u0, u1, u2, u3);
    }
  } else {
    #pragma unroll
    for (int r = 0; r < 8; ++r) {
      float bb = bi[l0 + r];
      *(ushort4*)(v_bf + (size_t)(b * C_ + l0 + r) * N_ + n) =
          make_ushort4(f2bf(acc[r][0]+bb), f2bf(acc[r][1]+bb),
                       f2bf(acc[r][2]+bb), f2bf(acc[r][3]+bb));
    }
  }
}

// ---------------------------------------------------------------------------
// flash3: wave-independent flash attention. NO barriers, NO shared memory.
//   Wave owns tj-tile jw = blockIdx.x*64 + wave*16 (16 columns) and computes
//   QK (K-frags resident in regs) AND PV over ALL 256 c-rows for those
//   columns. P's C-layout -> B-layout transform is in-register via __shfl
//   (ds_bpermute): B-frag dword (k=8*quad+2j') comes from lane
//   l16 + 16*(2*(quad&1) + (j'>>1)), packed reg ppk[tt][j'&1], with
//   tt = 2*ks + (quad>=2) selected by cndmask after two pulls.
//   Loads batched 8-deep in register arrays so VMEM latency is exposed once
//   per 8 MFMAs, and with no barriers the scheduler prefetches across phases.
//   Partials combined via global fp32 atomicAdd into zeroed res/den;
//   normalization deferred to out_proj epilogue.
// grid (64, 4, 4) = (tj-blocks, i-segments, batch), block 256 (4 waves).
// ---------------------------------------------------------------------------
__global__ __launch_bounds__(256, 2) void flash3(
    const ushort* __restrict__ q_t, const ushort* __restrict__ k_t,
    const ushort* __restrict__ v_bf, float* __restrict__ res,
    float* __restrict__ den)
{
  const int tid  = threadIdx.x;
  const int lane = tid & 63;
  const int wave = tid >> 6;
  const int l16  = lane & 15;
  const int quad = lane >> 4;
  const int jw    = blockIdx.x * 64 + wave * 16;   // this wave's tj base
  const int ibase = blockIdx.y * 1024;
  const int b     = blockIdx.z;

  // K fragments for wave's 16 tj, full c=256: resident whole kernel (32 VGPR)
  s8v kf[8];
  {
    const ushort* kp = k_t + (size_t)(b * N_ + jw + l16) * C_ + quad * 8;
    #pragma unroll
    for (int cs = 0; cs < 8; ++cs) kf[cs] = *(const s8v*)(kp + cs * 32);
  }

  f4v acc[16];                       // c = m*16 + quad*4 + r, tj = jw + l16
  #pragma unroll
  for (int m = 0; m < 16; ++m) acc[m] = (f4v){0.f, 0.f, 0.f, 0.f};
  float dacc = 0.f;

  const ushort* qrow = q_t + ((size_t)(b * N_) + l16) * C_ + quad * 8;
  const ushort* vrow = v_bf + (size_t)(b * C_ + l16) * N_ + quad * 8;

  const int src0 = l16 + 16 * (2 * (quad & 1));  // shfl src for j' in {0,1}
  const int src1 = src0 + 16;                    // shfl src for j' in {2,3}
  const bool hi_half = (quad >= 2);              // selects tt = 2ks+1

  for (int it = 0; it < 16; ++it) {
    const int i0 = ibase + it * 64;
    uint ppk[4][2];

    // ---- QK: 4 independent 8-MFMA chains; q loads batched 8-deep ----
    #pragma unroll
    for (int tt = 0; tt < 4; ++tt) {
      const ushort* qp = qrow + (size_t)(i0 + tt * 16) * C_;
      s8v qa[8];
      #pragma unroll
      for (int cs = 0; cs < 8; ++cs) qa[cs] = *(const s8v*)(qp + cs * 32);
      f4v s = (f4v){0.f, 0.f, 0.f, 0.f};
      #pragma unroll
      for (int cs = 0; cs < 8; ++cs)
        s = __builtin_amdgcn_mfma_f32_16x16x32_bf16(qa[cs], kf[cs], s, 0, 0, 0);
      float e0 = __expf(s[0] * SCALE);
      float e1 = __expf(s[1] * SCALE);
      float e2 = __expf(s[2] * SCALE);
      float e3 = __expf(s[3] * SCALE);
      dacc += (e0 + e1) + (e2 + e3);
      ppk[tt][0] = (uint)f2bf(e0) | ((uint)f2bf(e1) << 16);  // r=0,1 (lower k)
      ppk[tt][1] = (uint)f2bf(e2) | ((uint)f2bf(e3) << 16);  // r=2,3
    }

    // ---- PV: in-register P transpose (shfl) + 16 c-tiles per ks ----
    #pragma unroll
    for (int ks = 0; ks < 2; ++ks) {
      const int t0 = 2 * ks, t1 = 2 * ks + 1;
      uint d0a = __shfl(ppk[t0][0], src0, 64), d0b = __shfl(ppk[t1][0], src0, 64);
      uint d1a = __shfl(ppk[t0][1], src0, 64), d1b = __shfl(ppk[t1][1], src0, 64);
      uint d2a = __shfl(ppk[t0][0], src1, 64), d2b = __shfl(ppk[t1][0], src1, 64);
      uint d3a = __shfl(ppk[t0][1], src1, 64), d3b = __shfl(ppk[t1][1], src1, 64);
      union { uint u[4]; s8v v; } pb;
      pb.u[0] = hi_half ? d0b : d0a;
      pb.u[1] = hi_half ? d1b : d1a;
      pb.u[2] = hi_half ? d2b : d2a;
      pb.u[3] = hi_half ? d3b : d3a;
      const ushort* vv = vrow + i0 + ks * 32;
      #pragma unroll
      for (int g = 0; g < 2; ++g) {
        s8v av[8];
        #pragma unroll
        for (int mm = 0; mm < 8; ++mm)
          av[mm] = *(const s8v*)(vv + (size_t)((g * 8 + mm) * 16) * N_);
        #pragma unroll
        for (int mm = 0; mm < 8; ++mm)
          acc[g * 8 + mm] =
              __builtin_amdgcn_mfma_f32_16x16x32_bf16(av[mm], pb.v, acc[g * 8 + mm], 0, 0, 0);
      }
    }
  }

  // ---- denom: lanes l, l^16, l^32 share tj=l16; butterfly, one atomic/tj ----
  dacc += __shfl_xor(dacc, 16);
  dacc += __shfl_xor(dacc, 32);
  if (lane < 16) atomicAdd(&den[b * N_ + jw + lane], dacc);

  // ---- numerator partial into zeroed res ----
  #pragma unroll
  for (int m = 0; m < 16; ++m)
    #pragma unroll
    for (int r = 0; r < 4; ++r)
      atomicAdd(&res[(size_t)(b * C_ + m * 16 + quad * 4 + r) * N_ + jw + l16],
                acc[m][r]);
}

// ---------------------------------------------------------------------------
// Output projection with fused softmax normalization:
//   out[b][co][n] = bo[co] + (sum_l Wo[co][l] * res[b][l][n]) / den[b][n]
// grid (4, 32, 4), block 256. (unchanged from R2)
// ---------------------------------------------------------------------------
__global__ __launch_bounds__(256) void out_proj(
    const float* __restrict__ res, const float* __restrict__ Wo,
    const float* __restrict__ bo, const float* __restrict__ den,
    float* __restrict__ out)
{
  const int b  = blockIdx.z;
  const int l0 = blockIdx.y * 8;
  const int n  = blockIdx.x * 1024 + threadIdx.x * 4;

  __shared__ float w_lds[8 * 256];
  for (int i = threadIdx.x; i < 2048; i += 256) w_lds[i] = Wo[l0 * 256 + i];
  __syncthreads();

  float acc[8][4];
  #pragma unroll
  for (int r = 0; r < 8; ++r) { acc[r][0]=0.f; acc[r][1]=0.f; acc[r][2]=0.f; acc[r][3]=0.f; }

  const float* rp = res + (size_t)b * ((size_t)C_ * N_) + n;
  for (int c4 = 0; c4 < 256; c4 += 4) {
    float4 x0 = *(const float4*)(rp + (size_t)(c4 + 0) * N_);
    float4 x1 = *(const float4*)(rp + (size_t)(c4 + 1) * N_);
    float4 x2 = *(const float4*)(rp + (size_t)(c4 + 2) * N_);
    float4 x3 = *(const float4*)(rp + (size_t)(c4 + 3) * N_);
    #pragma unroll
    for (int r = 0; r < 8; ++r) {
      float4 w = *(const float4*)&w_lds[r * 256 + c4];
      acc[r][0] += w.x * x0.x + w.y * x1.x + w.z * x2.x + w.w * x3.x;
      acc[r][1] += w.x * x0.y + w.y * x1.y + w.z * x2.y + w.w * x3.y;
      acc[r][2] += w.x * x0.z + w.y * x1.z + w.z * x2.z + w.w * x3.z;
      acc[r][3] += w.x * x0.w + w.y * x1.w + w.z * x2.w + w.w * x3.w;
    }
  }

  float4 dv = *(const float4*)(den + (size_t)b * N_ + n);
  float di0 = 1.0f / dv.x, di1 = 1.0f / dv.y, di2 = 1.0f / dv.z, di3 = 1.0f / dv.w;

  #pragma unroll
  for (int r = 0; r < 8; ++r) {
    float bb = bo[l0 + r];
    *(float4*)(out + (size_t)(b * C_ + l0 + r) * N_ + n) =
        make_float4(acc[r][0]*di0 + bb, acc[r][1]*di1 + bb,
                    acc[r][2]*di2 + bb, acc[r][3]*di3 + bb);
  }
}

// ---------------------------------------------------------------------------
extern "C" void kernel_launch(void* const* d_in, const int* in_sizes, int n_in,
                              void* d_out, int out_size, void* d_ws, size_t ws_size,
                              hipStream_t stream)
{
  const float* x  = (const float*)d_in[0];
  const float* Wq = (const float*)d_in[1];
  const float* bq = (const float*)d_in[2];
  const float* Wk = (const float*)d_in[3];
  const float* bk = (const float*)d_in[4];
  const float* Wv = (const float*)d_in[5];
  const float* bv = (const float*)d_in[6];
  const float* Wo = (const float*)d_in[7];
  const float* bo = (const float*)d_in[8];
  float* out = (float*)d_out;

  // workspace layout (40 MB + 64 KB):
  //   q_t  [B][N][L] bf16  : 8 MB   (transposed)
  //   k_t  [B][N][L] bf16  : 8 MB   (transposed)
  //   v_bf [B][L][N] bf16  : 8 MB   (natural)
  //   res  [B][L][N] fp32  : 16 MB  (unnormalized numerator, atomic target)
  //   den  [B][N]    fp32  : 64 KB  (softmax denominators, atomic target)
  char* ws = (char*)d_ws;
  ushort* q_t  = (ushort*)(ws);
  ushort* k_t  = (ushort*)(ws + (size_t)8  * 1024 * 1024);
  ushort* v_bf = (ushort*)(ws + (size_t)16 * 1024 * 1024);
  float*  res  = (float*) (ws + (size_t)24 * 1024 * 1024);
  float*  den  = (float*) (ws + (size_t)40 * 1024 * 1024);

  // zero the atomic targets (res and den are contiguous)
  hipMemsetAsync(res, 0, (size_t)16 * 1024 * 1024 + (size_t)B_ * N_ * sizeof(float), stream);

  qkv_proj<<<dim3(4, 32, 12), dim3(256), 0, stream>>>(x, Wq, bq, Wk, bk, Wv, bv, q_t, k_t, v_bf);
  flash3<<<dim3(64, 4, 4), dim3(256), 0, stream>>>(q_t, k_t, v_bf, res, den);
  out_proj<<<dim3(4, 32, 4), dim3(256), 0, stream>>>(res, Wo, bo, den, out);
}

// Round 4
// 339.697 us; speedup vs baseline: 2.1762x; 2.1762x over previous
//
#include <hip/hip_runtime.h>

#define B_  4
#define C_  256     // C_IN == LATENT == 256
#define N_  4096    // H*W
#define SCALE 0.0625f   // 1/sqrt(256)

typedef short s8v __attribute__((ext_vector_type(8)));
typedef float f4v __attribute__((ext_vector_type(4)));

// round-to-nearest-even fp32 -> bf16 (values are finite; no NaN handling needed)
static __device__ __forceinline__ ushort f2bf(float f) {
  union { float f; uint u; } v; v.f = f;
  return (ushort)((v.u + 0x7FFFu + ((v.u >> 16) & 1u)) >> 16);
}

// ---------------------------------------------------------------------------
// QKV projection, fp32 compute, bf16 outputs (unchanged from R1/R2 — correct).
//   q,k written TRANSPOSED as [b][n][latent]; v natural [b][latent][n].
// grid (4, 32, 12), block 256.
// ---------------------------------------------------------------------------
__global__ __launch_bounds__(256) void qkv_proj(
    const float* __restrict__ x,
    const float* __restrict__ Wq, const float* __restrict__ bq,
    const float* __restrict__ Wk, const float* __restrict__ bk,
    const float* __restrict__ Wv, const float* __restrict__ bv,
    ushort* __restrict__ q_t, ushort* __restrict__ k_t, ushort* __restrict__ v_bf)
{
  const int p = blockIdx.z >> 2;
  const int b = blockIdx.z & 3;
  const float* W  = (p == 0) ? Wq : (p == 1) ? Wk : Wv;
  const float* bi = (p == 0) ? bq : (p == 1) ? bk : bv;
  const int l0 = blockIdx.y * 8;
  const int n  = blockIdx.x * 1024 + threadIdx.x * 4;

  __shared__ float w_lds[8 * 256];
  for (int i = threadIdx.x; i < 2048; i += 256) w_lds[i] = W[l0 * 256 + i];
  __syncthreads();

  float acc[8][4];
  #pragma unroll
  for (int r = 0; r < 8; ++r) { acc[r][0]=0.f; acc[r][1]=0.f; acc[r][2]=0.f; acc[r][3]=0.f; }

  const float* xp = x + (size_t)b * ((size_t)C_ * N_) + n;
  for (int c4 = 0; c4 < 256; c4 += 4) {
    float4 x0 = *(const float4*)(xp + (size_t)(c4 + 0) * N_);
    float4 x1 = *(const float4*)(xp + (size_t)(c4 + 1) * N_);
    float4 x2 = *(const float4*)(xp + (size_t)(c4 + 2) * N_);
    float4 x3 = *(const float4*)(xp + (size_t)(c4 + 3) * N_);
    #pragma unroll
    for (int r = 0; r < 8; ++r) {
      float4 w = *(const float4*)&w_lds[r * 256 + c4];
      acc[r][0] += w.x * x0.x + w.y * x1.x + w.z * x2.x + w.w * x3.x;
      acc[r][1] += w.x * x0.y + w.y * x1.y + w.z * x2.y + w.w * x3.y;
      acc[r][2] += w.x * x0.z + w.y * x1.z + w.z * x2.z + w.w * x3.z;
      acc[r][3] += w.x * x0.w + w.y * x1.w + w.z * x2.w + w.w * x3.w;
    }
  }

  if (p < 2) {
    ushort* outp = (p == 0) ? q_t : k_t;
    #pragma unroll
    for (int j = 0; j < 4; ++j) {
      uint u0 = (uint)f2bf(acc[0][j] + bi[l0+0]) | ((uint)f2bf(acc[1][j] + bi[l0+1]) << 16);
      uint u1 = (uint)f2bf(acc[2][j] + bi[l0+2]) | ((uint)f2bf(acc[3][j] + bi[l0+3]) << 16);
      uint u2 = (uint)f2bf(acc[4][j] + bi[l0+4]) | ((uint)f2bf(acc[5][j] + bi[l0+5]) << 16);
      uint u3 = (uint)f2bf(acc[6][j] + bi[l0+6]) | ((uint)f2bf(acc[7][j] + bi[l0+7]) << 16);
      *(uint4*)(outp + (size_t)(b * N_ + n + j) * C_ + l0) = make_uint4(u0, u1, u2, u3);
    }
  } else {
    #pragma unroll
    for (int r = 0; r < 8; ++r) {
      float bb = bi[l0 + r];
      *(ushort4*)(v_bf + (size_t)(b * C_ + l0 + r) * N_ + n) =
          make_ushort4(f2bf(acc[r][0]+bb), f2bf(acc[r][1]+bb),
                       f2bf(acc[r][2]+bb), f2bf(acc[r][3]+bb));
    }
  }
}

// ---------------------------------------------------------------------------
// flash4: m97-style fused attention. Block = 8 waves, TJ=128 tj-columns,
// BI=64 i-rows per iteration, 32 iterations (i-segment of 2048).
//
//   Per block: k-frags for all 128 tj x 256 c live in REGISTERS (wave w holds
//   tj range (w&3)*32..+31: kf[2][8], 64 VGPR), loaded once.
//   Per iter: q-chunk [64i][256c] bf16 staged to LDS (coalesced 16B global
//   loads -> padded ds_write_b128, row stride 264 ushorts = odd 16B stride).
//   QK: wave computes 2 tj-tiles x 2 i-tiles (32 MFMA) with A-frags from
//   LDS (16 ds_read_b128). exp -> P to LDS [128tj][72] (C-layout b64 writes).
//   PV: wave owns c-range (w&3)*64 x tj-range (w>>2)*64: 16 acc tiles,
//   32 MFMA; P B-frags 8 ds_read_b128; v A-frags 8x16B global issued at TOP
//   of iter (latency overlapped with QK phase + barrier drain).
//   2 barriers/iter. Partials via global atomicAdd into zeroed res/den;
//   normalization deferred to out_proj.
// grid (32, 2, 4) = (tj-blocks, i-segments, batch), block 512 (8 waves).
// ---------------------------------------------------------------------------
__global__ __launch_bounds__(512, 2) void flash4(
    const ushort* __restrict__ q_t, const ushort* __restrict__ k_t,
    const ushort* __restrict__ v_bf, float* __restrict__ res,
    float* __restrict__ den)
{
  const int tid  = threadIdx.x;
  const int lane = tid & 63;
  const int wave = tid >> 6;
  const int l16  = lane & 15;
  const int quad = lane >> 4;
  const int jw    = blockIdx.x * 128;        // block tj base
  const int ibase = blockIdx.y * 2048;       // i-segment base
  const int b     = blockIdx.z;

  const int wqk_j = wave & 3;                // QK: tj-pair index (tj = wqk_j*32 + jt*16)
  const int wqk_i = wave >> 2;               // QK: i-pair index  (i  = (wqk_i*2+it)*16)
  const int wpv_c = wave & 3;                // PV: c-range (w&3)*64
  const int wpv_j = wave >> 2;               // PV: tj-range (w>>2)*64

  __shared__ __align__(16) ushort q_lds[64 * 264];   // [i][c], +8 pad/row (528B, odd 16B stride)
  __shared__ __align__(16) ushort p_lds[128 * 72];   // [tj][ti], +8 pad/row

  // ---- K fragments: wave's 32 tj x 256 c, resident whole kernel (64 VGPR) ----
  s8v kf[2][8];
  #pragma unroll
  for (int jt = 0; jt < 2; ++jt) {
    const ushort* kp = k_t + (size_t)(b * N_ + jw + wqk_j * 32 + jt * 16 + l16) * C_ + quad * 8;
    #pragma unroll
    for (int cs = 0; cs < 8; ++cs) kf[jt][cs] = *(const s8v*)(kp + cs * 32);
  }

  f4v acc[4][4];   // [m: c-tile][t: tj-tile]; c = wpv_c*64+m*16+quad*4+r, tj = wpv_j*64+t*16+l16
  #pragma unroll
  for (int m = 0; m < 4; ++m)
    #pragma unroll
    for (int t = 0; t < 4; ++t) acc[m][t] = (f4v){0.f, 0.f, 0.f, 0.f};
  float dacc0 = 0.f, dacc1 = 0.f;

  const ushort* vbase0 = v_bf + (size_t)(b * C_ + wpv_c * 64 + l16) * N_ + quad * 8;

  for (int it = 0; it < 32; ++it) {
    const int i0 = ibase + it * 64;

    // ---- stage q-chunk [64i][256c] -> LDS (coalesced loads, padded writes) ----
    {
      const ushort* qseg = q_t + ((size_t)(b * N_) + i0) * C_;
      uint4 d0, d1, d2, d3;
      int c0 = tid, c1 = tid + 512, c2 = tid + 1024, c3 = tid + 1536;  // 16B-chunk ids
      d0 = *(const uint4*)(qseg + (size_t)c0 * 8);
      d1 = *(const uint4*)(qseg + (size_t)c1 * 8);
      d2 = *(const uint4*)(qseg + (size_t)c2 * 8);
      d3 = *(const uint4*)(qseg + (size_t)c3 * 8);
      *(uint4*)&q_lds[(c0 >> 5) * 264 + (c0 & 31) * 8] = d0;
      *(uint4*)&q_lds[(c1 >> 5) * 264 + (c1 & 31) * 8] = d1;
      *(uint4*)&q_lds[(c2 >> 5) * 264 + (c2 & 31) * 8] = d2;
      *(uint4*)&q_lds[(c3 >> 5) * 264 + (c3 & 31) * 8] = d3;
    }

    // ---- v A-frags for this iter: issue now, consumed after P-barrier ----
    s8v av[4][2];
    #pragma unroll
    for (int m = 0; m < 4; ++m)
      #pragma unroll
      for (int ks = 0; ks < 2; ++ks)
        av[m][ks] = *(const s8v*)(vbase0 + (size_t)(m * 16) * N_ + i0 + ks * 32);

    __syncthreads();   // q ready

    // ---- QK: 2 i-tiles x 2 tj-tiles, A from LDS, B from registers ----
    #pragma unroll
    for (int itile = 0; itile < 2; ++itile) {
      const int i_loc = (wqk_i * 2 + itile) * 16;
      f4v s0 = (f4v){0.f, 0.f, 0.f, 0.f};
      f4v s1 = (f4v){0.f, 0.f, 0.f, 0.f};
      const ushort* qa_base = q_lds + (i_loc + l16) * 264 + quad * 8;
      #pragma unroll
      for (int cs = 0; cs < 8; ++cs) {
        s8v qa = *(const s8v*)(qa_base + cs * 32);
        s0 = __builtin_amdgcn_mfma_f32_16x16x32_bf16(qa, kf[0][cs], s0, 0, 0, 0);
        s1 = __builtin_amdgcn_mfma_f32_16x16x32_bf16(qa, kf[1][cs], s1, 0, 0, 0);
      }
      // exp + P write (C-layout): row i = i_loc+quad*4+r, col tj
      {
        float e0 = __expf(s0[0] * SCALE), e1 = __expf(s0[1] * SCALE);
        float e2 = __expf(s0[2] * SCALE), e3 = __expf(s0[3] * SCALE);
        dacc0 += (e0 + e1) + (e2 + e3);
        *(ushort4*)&p_lds[(wqk_j * 32 + l16) * 72 + i_loc + quad * 4] =
            make_ushort4(f2bf(e0), f2bf(e1), f2bf(e2), f2bf(e3));
      }
      {
        float e0 = __expf(s1[0] * SCALE), e1 = __expf(s1[1] * SCALE);
        float e2 = __expf(s1[2] * SCALE), e3 = __expf(s1[3] * SCALE);
        dacc1 += (e0 + e1) + (e2 + e3);
        *(ushort4*)&p_lds[(wqk_j * 32 + 16 + l16) * 72 + i_loc + quad * 4] =
            make_ushort4(f2bf(e0), f2bf(e1), f2bf(e2), f2bf(e3));
      }
    }

    __syncthreads();   // P ready (also drains av loads)

    // ---- PV: 4 c-tiles x 4 tj-tiles, A = av regs, B from p_lds ----
    #pragma unroll
    for (int ks = 0; ks < 2; ++ks) {
      s8v pb[4];
      #pragma unroll
      for (int t = 0; t < 4; ++t)
        pb[t] = *(const s8v*)&p_lds[(wpv_j * 64 + t * 16 + l16) * 72 + ks * 32 + quad * 8];
      #pragma unroll
      for (int m = 0; m < 4; ++m)
        #pragma unroll
        for (int t = 0; t < 4; ++t)
          acc[m][t] = __builtin_amdgcn_mfma_f32_16x16x32_bf16(av[m][ks], pb[t], acc[m][t], 0, 0, 0);
    }
  }

  // ---- denom: reduce over quads (lanes l, l^16, l^32 share tj), 2 atomics ----
  dacc0 += __shfl_xor(dacc0, 16);  dacc0 += __shfl_xor(dacc0, 32);
  dacc1 += __shfl_xor(dacc1, 16);  dacc1 += __shfl_xor(dacc1, 32);
  if (lane < 16) {
    atomicAdd(&den[b * N_ + jw + wqk_j * 32 + lane], dacc0);
    atomicAdd(&den[b * N_ + jw + wqk_j * 32 + 16 + lane], dacc1);
  }

  // ---- numerator partials into zeroed res ----
  #pragma unroll
  for (int m = 0; m < 4; ++m)
    #pragma unroll
    for (int t = 0; t < 4; ++t)
      #pragma unroll
      for (int r = 0; r < 4; ++r)
        atomicAdd(&res[(size_t)(b * C_ + wpv_c * 64 + m * 16 + quad * 4 + r) * N_
                       + jw + wpv_j * 64 + t * 16 + l16],
                  acc[m][t][r]);
}

// ---------------------------------------------------------------------------
// Output projection with fused softmax normalization:
//   out[b][co][n] = bo[co] + (sum_l Wo[co][l] * res[b][l][n]) / den[b][n]
// grid (4, 32, 4), block 256. (unchanged from R2)
// ---------------------------------------------------------------------------
__global__ __launch_bounds__(256) void out_proj(
    const float* __restrict__ res, const float* __restrict__ Wo,
    const float* __restrict__ bo, const float* __restrict__ den,
    float* __restrict__ out)
{
  const int b  = blockIdx.z;
  const int l0 = blockIdx.y * 8;
  const int n  = blockIdx.x * 1024 + threadIdx.x * 4;

  __shared__ float w_lds[8 * 256];
  for (int i = threadIdx.x; i < 2048; i += 256) w_lds[i] = Wo[l0 * 256 + i];
  __syncthreads();

  float acc[8][4];
  #pragma unroll
  for (int r = 0; r < 8; ++r) { acc[r][0]=0.f; acc[r][1]=0.f; acc[r][2]=0.f; acc[r][3]=0.f; }

  const float* rp = res + (size_t)b * ((size_t)C_ * N_) + n;
  for (int c4 = 0; c4 < 256; c4 += 4) {
    float4 x0 = *(const float4*)(rp + (size_t)(c4 + 0) * N_);
    float4 x1 = *(const float4*)(rp + (size_t)(c4 + 1) * N_);
    float4 x2 = *(const float4*)(rp + (size_t)(c4 + 2) * N_);
    float4 x3 = *(const float4*)(rp + (size_t)(c4 + 3) * N_);
    #pragma unroll
    for (int r = 0; r < 8; ++r) {
      float4 w = *(const float4*)&w_lds[r * 256 + c4];
      acc[r][0] += w.x * x0.x + w.y * x1.x + w.z * x2.x + w.w * x3.x;
      acc[r][1] += w.x * x0.y + w.y * x1.y + w.z * x2.y + w.w * x3.y;
      acc[r][2] += w.x * x0.z + w.y * x1.z + w.z * x2.z + w.w * x3.z;
      acc[r][3] += w.x * x0.w + w.y * x1.w + w.z * x2.w + w.w * x3.w;
    }
  }

  float4 dv = *(const float4*)(den + (size_t)b * N_ + n);
  float di0 = 1.0f / dv.x, di1 = 1.0f / dv.y, di2 = 1.0f / dv.z, di3 = 1.0f / dv.w;

  #pragma unroll
  for (int r = 0; r < 8; ++r) {
    float bb = bo[l0 + r];
    *(float4*)(out + (size_t)(b * C_ + l0 + r) * N_ + n) =
        make_float4(acc[r][0]*di0 + bb, acc[r][1]*di1 + bb,
                    acc[r][2]*di2 + bb, acc[r][3]*di3 + bb);
  }
}

// ---------------------------------------------------------------------------
extern "C" void kernel_launch(void* const* d_in, const int* in_sizes, int n_in,
                              void* d_out, int out_size, void* d_ws, size_t ws_size,
                              hipStream_t stream)
{
  const float* x  = (const float*)d_in[0];
  const float* Wq = (const float*)d_in[1];
  const float* bq = (const float*)d_in[2];
  const float* Wk = (const float*)d_in[3];
  const float* bk = (const float*)d_in[4];
  const float* Wv = (const float*)d_in[5];
  const float* bv = (const float*)d_in[6];
  const float* Wo = (const float*)d_in[7];
  const float* bo = (const float*)d_in[8];
  float* out = (float*)d_out;

  // workspace layout (40 MB + 64 KB):
  //   q_t  [B][N][L] bf16  : 8 MB   (transposed)
  //   k_t  [B][N][L] bf16  : 8 MB   (transposed)
  //   v_bf [B][L][N] bf16  : 8 MB   (natural)
  //   res  [B][L][N] fp32  : 16 MB  (unnormalized numerator, atomic target)
  //   den  [B][N]    fp32  : 64 KB  (softmax denominators, atomic target)
  char* ws = (char*)d_ws;
  ushort* q_t  = (ushort*)(ws);
  ushort* k_t  = (ushort*)(ws + (size_t)8  * 1024 * 1024);
  ushort* v_bf = (ushort*)(ws + (size_t)16 * 1024 * 1024);
  float*  res  = (float*) (ws + (size_t)24 * 1024 * 1024);
  float*  den  = (float*) (ws + (size_t)40 * 1024 * 1024);

  // zero the atomic targets (res and den are contiguous)
  hipMemsetAsync(res, 0, (size_t)16 * 1024 * 1024 + (size_t)B_ * N_ * sizeof(float), stream);

  qkv_proj<<<dim3(4, 32, 12), dim3(256), 0, stream>>>(x, Wq, bq, Wk, bk, Wv, bv, q_t, k_t, v_bf);
  flash4<<<dim3(32, 2, 4), dim3(512), 0, stream>>>(q_t, k_t, v_bf, res, den);
  out_proj<<<dim3(4, 32, 4), dim3(256), 0, stream>>>(res, Wo, bo, den, out);
}

// Round 6
// 286.499 us; speedup vs baseline: 2.5802x; 1.1857x over previous
//
#include <hip/hip_runtime.h>

#define B_  4
#define C_  256     // C_IN == LATENT == 256
#define N_  4096    // H*W
#define SCALE 0.0625f   // 1/sqrt(256)

typedef short s8v __attribute__((ext_vector_type(8)));
typedef float f4v __attribute__((ext_vector_type(4)));

// round-to-nearest-even fp32 -> bf16 (values are finite; no NaN handling needed)
static __device__ __forceinline__ ushort f2bf(float f) {
  union { float f; uint u; } v; v.f = f;
  return (ushort)((v.u + 0x7FFFu + ((v.u >> 16) & 1u)) >> 16);
}

// ---------------------------------------------------------------------------
// xpose_cast: x [b][c][n] fp32  ->  x_t [b][n][c] bf16.
// 64x64 tiles through LDS (+1 pad). grid (64, 4, 4) = (n-tile, c-tile, b).
// ---------------------------------------------------------------------------
__global__ __launch_bounds__(256) void xpose_cast(
    const float* __restrict__ x, ushort* __restrict__ x_t)
{
  const int b  = blockIdx.z;
  const int c0 = blockIdx.y * 64;
  const int n0 = blockIdx.x * 64;
  __shared__ float t[64][65];

  const int tc = threadIdx.x >> 4;          // 0..15
  const int tn = (threadIdx.x & 15) * 4;    // 0..60
  #pragma unroll
  for (int cc = 0; cc < 64; cc += 16) {
    float4 v = *(const float4*)(x + (size_t)(b * C_ + c0 + cc + tc) * N_ + n0 + tn);
    t[cc + tc][tn + 0] = v.x;
    t[cc + tc][tn + 1] = v.y;
    t[cc + tc][tn + 2] = v.z;
    t[cc + tc][tn + 3] = v.w;
  }
  __syncthreads();

  const int on = threadIdx.x >> 2;          // 0..63 (n-local)
  const int oc = (threadIdx.x & 3) * 16;    // 0..48 (c-local chunk)
  union { ushort us[16]; uint4 q[2]; } o;
  #pragma unroll
  for (int i = 0; i < 16; ++i) o.us[i] = f2bf(t[oc + i][on]);
  ushort* dst = x_t + (size_t)(b * N_ + n0 + on) * C_ + c0 + oc;
  *(uint4*)dst       = o.q[0];
  *(uint4*)(dst + 8) = o.q[1];
}

// ---------------------------------------------------------------------------
// qkv_mfma: bf16 MFMA projection.  out = x * W^T (+bias), three projections.
//   A = x_t rows (n), k = c;  B = W rows (l), k = c  -> D: col=l, row=n.
//   W-tile (64 l x 256 c) staged to LDS once, then held as register B-frags
//   (kw[4][8], loop-invariant). x-chunk (64 n x 256 c) staged per iter like
//   flash4's q staging. 32 MFMA per wave-iter vs 8 LDS A-reads.
//   q,k stored [b][n][l] (2B stores, 32B-contiguous per quad-row);
//   v stored [b][c][n] (ushort4, n-consecutive).
// grid (8, 4, 12) = (n-seg of 512, l-range of 64, proj*4+b), block 256.
// ---------------------------------------------------------------------------
__global__ __launch_bounds__(256, 2) void qkv_mfma(
    const ushort* __restrict__ x_t,
    const float* __restrict__ Wq, const float* __restrict__ bq,
    const float* __restrict__ Wk, const float* __restrict__ bk,
    const float* __restrict__ Wv, const float* __restrict__ bv,
    ushort* __restrict__ q_t, ushort* __restrict__ k_t, ushort* __restrict__ v_bf)
{
  const int p = blockIdx.z >> 2;
  const int b = blockIdx.z & 3;
  const float* W  = (p == 0) ? Wq : (p == 1) ? Wk : Wv;
  const float* bi = (p == 0) ? bq : (p == 1) ? bk : bv;
  const int l0    = blockIdx.y * 64;
  const int nseg  = blockIdx.x * 512;

  const int tid  = threadIdx.x;
  const int lane = tid & 63;
  const int wave = tid >> 6;
  const int l16  = lane & 15;
  const int quad = lane >> 4;

  __shared__ __align__(16) ushort w_lds[64 * 264];
  __shared__ __align__(16) ushort x_lds[64 * 264];

  // stage W tile [64 l][256 c] fp32 -> bf16 LDS
  for (int g = tid; g < 4096; g += 256) {
    int row = g >> 6, col4 = (g & 63) * 4;
    float4 wv = *(const float4*)(W + (size_t)(l0 + row) * 256 + col4);
    *(ushort4*)&w_lds[row * 264 + col4] =
        make_ushort4(f2bf(wv.x), f2bf(wv.y), f2bf(wv.z), f2bf(wv.w));
  }
  __syncthreads();

  // B-frags: W rows l = l0 + lt*16 + l16, k = quad*8 + cs*32 + j  (loop-invariant)
  s8v kw[4][8];
  #pragma unroll
  for (int lt = 0; lt < 4; ++lt)
    #pragma unroll
    for (int cs = 0; cs < 8; ++cs)
      kw[lt][cs] = *(const s8v*)&w_lds[(lt * 16 + l16) * 264 + quad * 8 + cs * 32];

  // bias per lane-column (fp32, hoisted)
  float bias_l[4];
  #pragma unroll
  for (int lt = 0; lt < 4; ++lt) bias_l[lt] = bi[l0 + lt * 16 + l16];

  for (int it = 0; it < 8; ++it) {
    const int n0 = nseg + it * 64;

    // stage x chunk [64 n][256 c] bf16 (contiguous b128 copies)
    {
      const ushort* xseg = x_t + (size_t)(b * N_ + n0) * C_;
      #pragma unroll
      for (int k = 0; k < 8; ++k) {
        int c = tid + k * 256;
        uint4 d = *(const uint4*)(xseg + (size_t)c * 8);
        *(uint4*)&x_lds[(c >> 5) * 264 + (c & 31) * 8] = d;
      }
    }
    __syncthreads();

    f4v s[4];
    #pragma unroll
    for (int lt = 0; lt < 4; ++lt) s[lt] = (f4v){0.f, 0.f, 0.f, 0.f};
    const ushort* xa_base = x_lds + (wave * 16 + l16) * 264 + quad * 8;
    #pragma unroll
    for (int cs = 0; cs < 8; ++cs) {
      s8v xa = *(const s8v*)(xa_base + cs * 32);
      #pragma unroll
      for (int lt = 0; lt < 4; ++lt)
        s[lt] = __builtin_amdgcn_mfma_f32_16x16x32_bf16(xa, kw[lt][cs], s[lt], 0, 0, 0);
    }

    // epilogue: D col = l0+lt*16+l16, rows n = n0 + wave*16 + quad*4 + r
    const int nb = n0 + wave * 16 + quad * 4;
    if (p < 2) {
      ushort* outp = (p == 0) ? q_t : k_t;
      #pragma unroll
      for (int lt = 0; lt < 4; ++lt) {
        const int l = l0 + lt * 16 + l16;
        #pragma unroll
        for (int r = 0; r < 4; ++r)
          outp[(size_t)(b * N_ + nb + r) * C_ + l] = f2bf(s[lt][r] + bias_l[lt]);
      }
    } else {
      #pragma unroll
      for (int lt = 0; lt < 4; ++lt) {
        const int c_out = l0 + lt * 16 + l16;
        *(ushort4*)&v_bf[(size_t)(b * C_ + c_out) * N_ + nb] =
            make_ushort4(f2bf(s[lt][0] + bias_l[lt]), f2bf(s[lt][1] + bias_l[lt]),
                         f2bf(s[lt][2] + bias_l[lt]), f2bf(s[lt][3] + bias_l[lt]));
      }
    }
    __syncthreads();
  }
}

// ---------------------------------------------------------------------------
// flash5: identical structure to flash4 (R4-verified), but 4 i-segments
// -> grid 512 blocks = 2 blocks/CU so barrier drains overlap across blocks.
// grid (32, 4, 4) = (tj-blocks, i-segments, batch), block 512 (8 waves).
// ---------------------------------------------------------------------------
__global__ __launch_bounds__(512, 2) void flash5(
    const ushort* __restrict__ q_t, const ushort* __restrict__ k_t,
    const ushort* __restrict__ v_bf, float* __restrict__ res,
    float* __restrict__ den)
{
  const int tid  = threadIdx.x;
  const int lane = tid & 63;
  const int wave = tid >> 6;
  const int l16  = lane & 15;
  const int quad = lane >> 4;
  const int jw    = blockIdx.x * 128;        // block tj base
  const int ibase = blockIdx.y * 1024;       // i-segment base
  const int b     = blockIdx.z;

  const int wqk_j = wave & 3;                // QK: tj-pair index
  const int wqk_i = wave >> 2;               // QK: i-pair index
  const int wpv_c = wave & 3;                // PV: c-range (w&3)*64
  const int wpv_j = wave >> 2;               // PV: tj-range (w>>2)*64

  __shared__ __align__(16) ushort q_lds[64 * 264];   // [i][c], +8 pad/row
  __shared__ __align__(16) ushort p_lds[128 * 72];   // [tj][ti], +8 pad/row

  // K fragments: wave's 32 tj x 256 c, resident whole kernel (64 VGPR)
  s8v kf[2][8];
  #pragma unroll
  for (int jt = 0; jt < 2; ++jt) {
    const ushort* kp = k_t + (size_t)(b * N_ + jw + wqk_j * 32 + jt * 16 + l16) * C_ + quad * 8;
    #pragma unroll
    for (int cs = 0; cs < 8; ++cs) kf[jt][cs] = *(const s8v*)(kp + cs * 32);
  }

  f4v acc[4][4];
  #pragma unroll
  for (int m = 0; m < 4; ++m)
    #pragma unroll
    for (int t = 0; t < 4; ++t) acc[m][t] = (f4v){0.f, 0.f, 0.f, 0.f};
  float dacc0 = 0.f, dacc1 = 0.f;

  const ushort* vbase0 = v_bf + (size_t)(b * C_ + wpv_c * 64 + l16) * N_ + quad * 8;

  for (int it = 0; it < 16; ++it) {
    const int i0 = ibase + it * 64;

    // stage q-chunk [64 i][256 c] -> LDS
    {
      const ushort* qseg = q_t + ((size_t)(b * N_) + i0) * C_;
      int c0 = tid, c1 = tid + 512, c2 = tid + 1024, c3 = tid + 1536;
      uint4 d0 = *(const uint4*)(qseg + (size_t)c0 * 8);
      uint4 d1 = *(const uint4*)(qseg + (size_t)c1 * 8);
      uint4 d2 = *(const uint4*)(qseg + (size_t)c2 * 8);
      uint4 d3 = *(const uint4*)(qseg + (size_t)c3 * 8);
      *(uint4*)&q_lds[(c0 >> 5) * 264 + (c0 & 31) * 8] = d0;
      *(uint4*)&q_lds[(c1 >> 5) * 264 + (c1 & 31) * 8] = d1;
      *(uint4*)&q_lds[(c2 >> 5) * 264 + (c2 & 31) * 8] = d2;
      *(uint4*)&q_lds[(c3 >> 5) * 264 + (c3 & 31) * 8] = d3;
    }

    // v A-frags: issue now, consumed after P-barrier
    s8v av[4][2];
    #pragma unroll
    for (int m = 0; m < 4; ++m)
      #pragma unroll
      for (int ks = 0; ks < 2; ++ks)
        av[m][ks] = *(const s8v*)(vbase0 + (size_t)(m * 16) * N_ + i0 + ks * 32);

    __syncthreads();   // q ready

    // QK: 2 i-tiles x 2 tj-tiles, A from LDS, B from registers
    #pragma unroll
    for (int itile = 0; itile < 2; ++itile) {
      const int i_loc = (wqk_i * 2 + itile) * 16;
      f4v s0 = (f4v){0.f, 0.f, 0.f, 0.f};
      f4v s1 = (f4v){0.f, 0.f, 0.f, 0.f};
      const ushort* qa_base = q_lds + (i_loc + l16) * 264 + quad * 8;
      #pragma unroll
      for (int cs = 0; cs < 8; ++cs) {
        s8v qa = *(const s8v*)(qa_base + cs * 32);
        s0 = __builtin_amdgcn_mfma_f32_16x16x32_bf16(qa, kf[0][cs], s0, 0, 0, 0);
        s1 = __builtin_amdgcn_mfma_f32_16x16x32_bf16(qa, kf[1][cs], s1, 0, 0, 0);
      }
      {
        float e0 = __expf(s0[0] * SCALE), e1 = __expf(s0[1] * SCALE);
        float e2 = __expf(s0[2] * SCALE), e3 = __expf(s0[3] * SCALE);
        dacc0 += (e0 + e1) + (e2 + e3);
        *(ushort4*)&p_lds[(wqk_j * 32 + l16) * 72 + i_loc + quad * 4] =
            make_ushort4(f2bf(e0), f2bf(e1), f2bf(e2), f2bf(e3));
      }
      {
        float e0 = __expf(s1[0] * SCALE), e1 = __expf(s1[1] * SCALE);
        float e2 = __expf(s1[2] * SCALE), e3 = __expf(s1[3] * SCALE);
        dacc1 += (e0 + e1) + (e2 + e3);
        *(ushort4*)&p_lds[(wqk_j * 32 + 16 + l16) * 72 + i_loc + quad * 4] =
            make_ushort4(f2bf(e0), f2bf(e1), f2bf(e2), f2bf(e3));
      }
    }

    __syncthreads();   // P ready (also drains av loads)

    // PV: 4 c-tiles x 4 tj-tiles, A = av regs, B from p_lds
    #pragma unroll
    for (int ks = 0; ks < 2; ++ks) {
      s8v pb[4];
      #pragma unroll
      for (int t = 0; t < 4; ++t)
        pb[t] = *(const s8v*)&p_lds[(wpv_j * 64 + t * 16 + l16) * 72 + ks * 32 + quad * 8];
      #pragma unroll
      for (int m = 0; m < 4; ++m)
        #pragma unroll
        for (int t = 0; t < 4; ++t)
          acc[m][t] = __builtin_amdgcn_mfma_f32_16x16x32_bf16(av[m][ks], pb[t], acc[m][t], 0, 0, 0);
    }
  }

  // denom: lanes l, l^16, l^32 share tj; butterfly then one atomic per tj
  dacc0 += __shfl_xor(dacc0, 16);  dacc0 += __shfl_xor(dacc0, 32);
  dacc1 += __shfl_xor(dacc1, 16);  dacc1 += __shfl_xor(dacc1, 32);
  if (lane < 16) {
    atomicAdd(&den[b * N_ + jw + wqk_j * 32 + lane], dacc0);
    atomicAdd(&den[b * N_ + jw + wqk_j * 32 + 16 + lane], dacc1);
  }

  // numerator partials into zeroed res
  #pragma unroll
  for (int m = 0; m < 4; ++m)
    #pragma unroll
    for (int t = 0; t < 4; ++t)
      #pragma unroll
      for (int r = 0; r < 4; ++r)
        atomicAdd(&res[(size_t)(b * C_ + wpv_c * 64 + m * 16 + quad * 4 + r) * N_
                       + jw + wpv_j * 64 + t * 16 + l16],
                  acc[m][t][r]);
}

// ---------------------------------------------------------------------------
// Output projection with fused softmax normalization (unchanged from R2):
//   out[b][co][n] = bo[co] + (sum_l Wo[co][l] * res[b][l][n]) / den[b][n]
// grid (4, 32, 4), block 256.
// ---------------------------------------------------------------------------
__global__ __launch_bounds__(256) void out_proj(
    const float* __restrict__ res, const float* __restrict__ Wo,
    const float* __restrict__ bo, const float* __restrict__ den,
    float* __restrict__ out)
{
  const int b  = blockIdx.z;
  const int l0 = blockIdx.y * 8;
  const int n  = blockIdx.x * 1024 + threadIdx.x * 4;

  __shared__ float w_lds[8 * 256];
  for (int i = threadIdx.x; i < 2048; i += 256) w_lds[i] = Wo[l0 * 256 + i];
  __syncthreads();

  float acc[8][4];
  #pragma unroll
  for (int r = 0; r < 8; ++r) { acc[r][0]=0.f; acc[r][1]=0.f; acc[r][2]=0.f; acc[r][3]=0.f; }

  const float* rp = res + (size_t)b * ((size_t)C_ * N_) + n;
  for (int c4 = 0; c4 < 256; c4 += 4) {
    float4 x0 = *(const float4*)(rp + (size_t)(c4 + 0) * N_);
    float4 x1 = *(const float4*)(rp + (size_t)(c4 + 1) * N_);
    float4 x2 = *(const float4*)(rp + (size_t)(c4 + 2) * N_);
    float4 x3 = *(const float4*)(rp + (size_t)(c4 + 3) * N_);
    #pragma unroll
    for (int r = 0; r < 8; ++r) {
      float4 w = *(const float4*)&w_lds[r * 256 + c4];
      acc[r][0] += w.x * x0.x + w.y * x1.x + w.z * x2.x + w.w * x3.x;
      acc[r][1] += w.x * x0.y + w.y * x1.y + w.z * x2.y + w.w * x3.y;
      acc[r][2] += w.x * x0.z + w.y * x1.z + w.z * x2.z + w.w * x3.z;
      acc[r][3] += w.x * x0.w + w.y * x1.w + w.z * x2.w + w.w * x3.w;
    }
  }

  float4 dv = *(const float4*)(den + (size_t)b * N_ + n);
  float di0 = 1.0f / dv.x, di1 = 1.0f / dv.y, di2 = 1.0f / dv.z, di3 = 1.0f / dv.w;

  #pragma unroll
  for (int r = 0; r < 8; ++r) {
    float bb = bo[l0 + r];
    *(float4*)(out + (size_t)(b * C_ + l0 + r) * N_ + n) =
        make_float4(acc[r][0]*di0 + bb, acc[r][1]*di1 + bb,
                    acc[r][2]*di2 + bb, acc[r][3]*di3 + bb);
  }
}

// ---------------------------------------------------------------------------
extern "C" void kernel_launch(void* const* d_in, const int* in_sizes, int n_in,
                              void* d_out, int out_size, void* d_ws, size_t ws_size,
                              hipStream_t stream)
{
  const float* x  = (const float*)d_in[0];
  const float* Wq = (const float*)d_in[1];
  const float* bq = (const float*)d_in[2];
  const float* Wk = (const float*)d_in[3];
  const float* bk = (const float*)d_in[4];
  const float* Wv = (const float*)d_in[5];
  const float* bv = (const float*)d_in[6];
  const float* Wo = (const float*)d_in[7];
  const float* bo = (const float*)d_in[8];
  float* out = (float*)d_out;

  // workspace layout (48 MB + 128 KB):
  //   q_t  [B][N][L] bf16  : 8 MB   (transposed)
  //   k_t  [B][N][L] bf16  : 8 MB   (transposed)
  //   v_bf [B][L][N] bf16  : 8 MB   (natural)
  //   res  [B][L][N] fp32  : 16 MB  (unnormalized numerator, atomic target)
  //   den  [B][N]    fp32  : 64 KB  (softmax denominators, atomic target)
  //   x_t  [B][N][C] bf16  : 8 MB   (transposed+cast input)
  char* ws = (char*)d_ws;
  ushort* q_t  = (ushort*)(ws);
  ushort* k_t  = (ushort*)(ws + (size_t)8  * 1024 * 1024);
  ushort* v_bf = (ushort*)(ws + (size_t)16 * 1024 * 1024);
  float*  res  = (float*) (ws + (size_t)24 * 1024 * 1024);
  float*  den  = (float*) (ws + (size_t)40 * 1024 * 1024);
  ushort* x_t  = (ushort*)(ws + (size_t)40 * 1024 * 1024 + 65536);

  // zero the atomic targets (res and den are contiguous)
  (void)hipMemsetAsync(res, 0, (size_t)16 * 1024 * 1024 + (size_t)B_ * N_ * sizeof(float), stream);

  xpose_cast<<<dim3(64, 4, 4),  dim3(256), 0, stream>>>(x, x_t);
  qkv_mfma <<<dim3(8, 4, 12),   dim3(256), 0, stream>>>(x_t, Wq, bq, Wk, bk, Wv, bv, q_t, k_t, v_bf);
  flash5   <<<dim3(32, 4, 4),   dim3(512), 0, stream>>>(q_t, k_t, v_bf, res, den);
  out_proj <<<dim3(4, 32, 4),   dim3(256), 0, stream>>>(res, Wo, bo, den, out);
}